// Round 3
// baseline (2365.510 us; speedup 1.0000x reference)
//
#include <hip/hip_runtime.h>
#include <hip/hip_bf16.h>
#include <math.h>

#define EMBED 1024
#define HEADS 16
#define HDIM 64
#define RANK 8
#define SCALING 2.0f
#define BB 2
#define TT 2048
#define MTOT (BB * TT)

// W_eff[o][c] = W[o][c] + SCALING * sum_r A[c][r] * B[r][o]
__global__ void make_weff_kernel(const float* __restrict__ W,
                                 const float* __restrict__ A,
                                 const float* __restrict__ Bm,
                                 float* __restrict__ Weff) {
    int idx = blockIdx.x * 256 + threadIdx.x;   // over 1024*1024
    int o = idx >> 10;
    int c = idx & 1023;
    float s = 0.f;
#pragma unroll
    for (int r = 0; r < RANK; ++r)
        s += A[c * RANK + r] * Bm[r * EMBED + o];
    Weff[idx] = W[idx] + SCALING * s;
}

// C[m][o] = sum_c X[m][c] * W[o][c]
// MODE 0: plain store   MODE 1: remap to [b][h][t][d]   MODE 2: plain + bias
template<int MODE>
__global__ void gemm_bt_kernel(const float* __restrict__ X,
                               const float* __restrict__ W,
                               const float* __restrict__ bias,
                               float* __restrict__ C) {
    const int K = EMBED;
    __shared__ float Xs[16][65];
    __shared__ float Ws[16][65];
    int t  = threadIdx.x;
    int tx = t & 15, ty = t >> 4;
    int m0 = blockIdx.y * 64, n0 = blockIdx.x * 64;
    float acc[4][4] = {};
    for (int k0 = 0; k0 < K; k0 += 16) {
        __syncthreads();
#pragma unroll
        for (int i = 0; i < 4; ++i) {
            int linear = t + 256 * i;          // 0..1023
            int row = linear >> 4, kl = linear & 15;
            Xs[kl][row] = X[(size_t)(m0 + row) * K + k0 + kl];
            Ws[kl][row] = W[(size_t)(n0 + row) * K + k0 + kl];
        }
        __syncthreads();
#pragma unroll
        for (int k = 0; k < 16; ++k) {
            float a[4], b[4];
#pragma unroll
            for (int i = 0; i < 4; ++i) a[i] = Xs[k][ty * 4 + i];
#pragma unroll
            for (int j = 0; j < 4; ++j) b[j] = Ws[k][tx * 4 + j];
#pragma unroll
            for (int i = 0; i < 4; ++i)
#pragma unroll
                for (int j = 0; j < 4; ++j)
                    acc[i][j] += a[i] * b[j];
        }
    }
#pragma unroll
    for (int i = 0; i < 4; ++i) {
        int m = m0 + ty * 4 + i;
#pragma unroll
        for (int j = 0; j < 4; ++j) {
            int o = n0 + tx * 4 + j;
            float v = acc[i][j];
            if (MODE == 1) {
                int b = m >> 11, tt = m & 2047;
                int h = o >> 6,  d = o & 63;
                C[(((size_t)(b * HEADS + h) * TT) + tt) * HDIM + d] = v;
            } else {
                if (MODE == 2) v += bias[o];
                C[(size_t)m * EMBED + o] = v;
            }
        }
    }
}

// Flash attention fp32. Q,K,V: [B*H][T][D]. ctx out: [B][T][H*D] (= [m][1024]).
__global__ void attn_kernel(const float* __restrict__ Q,
                            const float* __restrict__ K,
                            const float* __restrict__ V,
                            float* __restrict__ ctx) {
    __shared__ float Qs[64][65];
    __shared__ float Ks[64][65];
    __shared__ float Vs[64][65];
    __shared__ float Ps[64][65];
    int t  = threadIdx.x;
    int tx = t & 15, ty = t >> 4;
    int bh = blockIdx.y;
    int q0 = blockIdx.x * 64;
    const float* Qb = Q + ((size_t)bh * TT + q0) * HDIM;
    const float* Kb = K + (size_t)bh * TT * HDIM;
    const float* Vb = V + (size_t)bh * TT * HDIM;

#pragma unroll
    for (int i = 0; i < 16; ++i) {
        int linear = t + 256 * i;              // 0..4095
        int r = linear >> 6, d = linear & 63;
        Qs[r][d] = Qb[r * HDIM + d] * 0.125f;  // fold 1/sqrt(64)
    }

    float mi[4], li[4], O[4][4];
#pragma unroll
    for (int i = 0; i < 4; ++i) {
        mi[i] = -1e30f; li[i] = 0.f;
#pragma unroll
        for (int j = 0; j < 4; ++j) O[i][j] = 0.f;
    }

    for (int k0 = 0; k0 < TT; k0 += 64) {
        __syncthreads();   // protect Ks/Vs (prev PV done), Qs on first iter
#pragma unroll
        for (int i = 0; i < 16; ++i) {
            int linear = t + 256 * i;
            int r = linear >> 6, d = linear & 63;
            Ks[r][d] = Kb[(size_t)(k0 + r) * HDIM + d];
            Vs[r][d] = Vb[(size_t)(k0 + r) * HDIM + d];
        }
        __syncthreads();

        float s[4][4] = {};
#pragma unroll
        for (int d = 0; d < 64; ++d) {
            float a[4], b[4];
#pragma unroll
            for (int i = 0; i < 4; ++i) a[i] = Qs[ty * 4 + i][d];
#pragma unroll
            for (int j = 0; j < 4; ++j) b[j] = Ks[tx * 4 + j][d];
#pragma unroll
            for (int i = 0; i < 4; ++i)
#pragma unroll
                for (int j = 0; j < 4; ++j)
                    s[i][j] += a[i] * b[j];
        }

#pragma unroll
        for (int i = 0; i < 4; ++i) {
            float mx = fmaxf(fmaxf(s[i][0], s[i][1]), fmaxf(s[i][2], s[i][3]));
#pragma unroll
            for (int off = 1; off < 16; off <<= 1)
                mx = fmaxf(mx, __shfl_xor(mx, off));
            float mnew  = fmaxf(mi[i], mx);
            float scale = __expf(mi[i] - mnew);
            float rs = 0.f;
#pragma unroll
            for (int j = 0; j < 4; ++j) {
                float p = __expf(s[i][j] - mnew);
                s[i][j] = p;
                rs += p;
            }
#pragma unroll
            for (int off = 1; off < 16; off <<= 1)
                rs += __shfl_xor(rs, off);
            li[i] = li[i] * scale + rs;
            mi[i] = mnew;
#pragma unroll
            for (int j = 0; j < 4; ++j) O[i][j] *= scale;
        }
#pragma unroll
        for (int i = 0; i < 4; ++i)
#pragma unroll
            for (int j = 0; j < 4; ++j)
                Ps[ty * 4 + i][tx * 4 + j] = s[i][j];
        __syncthreads();

#pragma unroll
        for (int k = 0; k < 64; ++k) {
            float a[4], b[4];
#pragma unroll
            for (int i = 0; i < 4; ++i) a[i] = Ps[ty * 4 + i][k];
#pragma unroll
            for (int j = 0; j < 4; ++j) b[j] = Vs[k][tx * 4 + j];
#pragma unroll
            for (int i = 0; i < 4; ++i)
#pragma unroll
                for (int j = 0; j < 4; ++j)
                    O[i][j] += a[i] * b[j];
        }
    }

    int b = bh >> 4, h = bh & 15;
#pragma unroll
    for (int i = 0; i < 4; ++i) {
        float inv = 1.f / li[i];
        int tq = q0 + ty * 4 + i;
#pragma unroll
        for (int j = 0; j < 4; ++j) {
            int d = tx * 4 + j;
            ctx[((size_t)b * TT + tq) * EMBED + h * HDIM + d] = O[i][j] * inv;
        }
    }
}

extern "C" void kernel_launch(void* const* d_in, const int* in_sizes, int n_in,
                              void* d_out, int out_size, void* d_ws, size_t ws_size,
                              hipStream_t stream) {
    const float* x  = (const float*)d_in[0];
    const float* Wq = (const float*)d_in[1];
    const float* Aq = (const float*)d_in[2];
    const float* Bq = (const float*)d_in[3];
    const float* Wk = (const float*)d_in[4];
    const float* Ak = (const float*)d_in[5];
    const float* Bk = (const float*)d_in[6];
    const float* Wv = (const float*)d_in[7];
    const float* Av = (const float*)d_in[8];
    const float* Bv = (const float*)d_in[9];
    const float* Wo = (const float*)d_in[10];
    const float* bo = (const float*)d_in[11];
    float* out = (float*)d_out;

    char* ws = (char*)d_ws;
    float* weff_q = (float*)(ws + ((size_t)0  << 20));  // 4 MB
    float* weff_k = (float*)(ws + ((size_t)4  << 20));  // 4 MB
    float* weff_v = (float*)(ws + ((size_t)8  << 20));  // 4 MB
    float* Qb     = (float*)(ws + ((size_t)12 << 20));  // 16 MB
    float* Kb     = (float*)(ws + ((size_t)28 << 20));  // 16 MB
    float* Vb     = (float*)(ws + ((size_t)44 << 20));  // 16 MB
    float* ctx    = (float*)(ws + ((size_t)60 << 20));  // 16 MB  (total 76 MB)

    dim3 blk(256);
    make_weff_kernel<<<dim3(4096), blk, 0, stream>>>(Wq, Aq, Bq, weff_q);
    make_weff_kernel<<<dim3(4096), blk, 0, stream>>>(Wk, Ak, Bk, weff_k);
    make_weff_kernel<<<dim3(4096), blk, 0, stream>>>(Wv, Av, Bv, weff_v);

    dim3 ggrid(EMBED / 64, MTOT / 64);
    gemm_bt_kernel<1><<<ggrid, blk, 0, stream>>>(x, weff_q, nullptr, Qb);
    gemm_bt_kernel<1><<<ggrid, blk, 0, stream>>>(x, weff_k, nullptr, Kb);
    gemm_bt_kernel<1><<<ggrid, blk, 0, stream>>>(x, weff_v, nullptr, Vb);

    dim3 agrid(TT / 64, MTOT / TT * HEADS);
    attn_kernel<<<agrid, blk, 0, stream>>>(Qb, Kb, Vb, ctx);

    gemm_bt_kernel<2><<<ggrid, blk, 0, stream>>>(ctx, Wo, bo, out);
}

// Round 4
// 415.168 us; speedup vs baseline: 5.6977x; 5.6977x over previous
//
#include <hip/hip_runtime.h>
#include <hip/hip_bf16.h>
#include <math.h>

#define EMBED 1024
#define HEADS 16
#define HDIM 64
#define RANK 8
#define BB 2
#define TT 2048
#define MTOT (BB*TT)
#define BH (BB*HEADS)

typedef __attribute__((ext_vector_type(8))) short bf16x8;
typedef __attribute__((ext_vector_type(4))) float f32x4;
typedef unsigned short u16;

__device__ __forceinline__ u16 f2bf(float f){
  unsigned u = __float_as_uint(f);
  u += 0x7FFF + ((u >> 16) & 1);          // RNE
  return (u16)(u >> 16);
}
__device__ __forceinline__ float bf2f(u16 h){ return __uint_as_float(((unsigned)h) << 16); }

__device__ __forceinline__ void stage16(const void* g, void* l){
  __builtin_amdgcn_global_load_lds((const __attribute__((address_space(1))) unsigned int*)g,
                                   (__attribute__((address_space(3))) unsigned int*)l, 16, 0, 0);
}

// ---------------- prep kernels ----------------
__global__ void split_x_kernel(const float* __restrict__ x, u16* __restrict__ xhi, u16* __restrict__ xlo){
  int i = blockIdx.x * 256 + threadIdx.x;           // 4M
  float v = x[i];
  u16 h = f2bf(v);
  xhi[i] = h;
  xlo[i] = f2bf(v - bf2f(h));
}

__global__ void weff_split_kernel(const float* __restrict__ W, const float* __restrict__ A,
                                  const float* __restrict__ Bm,
                                  u16* __restrict__ whi, u16* __restrict__ wlo){
  int i = blockIdx.x * 256 + threadIdx.x;           // 1M, i = o*1024+c
  int o = i >> 10, c = i & 1023;
  float s = 0.f;
#pragma unroll
  for (int r = 0; r < RANK; ++r) s += A[c*RANK+r] * Bm[r*EMBED+o];
  float v = W[i] + 2.0f * s;
  u16 h = f2bf(v);
  whi[i] = h;
  wlo[i] = f2bf(v - bf2f(h));
}

__global__ void weff_bf16_kernel(const float* __restrict__ W, const float* __restrict__ A,
                                 const float* __restrict__ Bm, u16* __restrict__ wb){
  int i = blockIdx.x * 256 + threadIdx.x;
  int o = i >> 10, c = i & 1023;
  float s = 0.f;
#pragma unroll
  for (int r = 0; r < RANK; ++r) s += A[c*RANK+r] * Bm[r*EMBED+o];
  wb[i] = f2bf(W[i] + 2.0f * s);
}

__global__ void bf16_cast_kernel(const float* __restrict__ W, u16* __restrict__ wb){
  int i = blockIdx.x * 256 + threadIdx.x;
  wb[i] = f2bf(W[i]);
}

// ---------------- MFMA GEMM: C[m][n] = sum_k A[m][k]*B[n][k] ----------------
// SPLIT=3: acc = Ah*Bh + Ah*Bl + Al*Bh (hi/lo bf16 emulation)
// EPI 0: scale, split hi/lo, store [bh][t][d]   EPI 1: bf16 store V^T [bh][d][t]
// EPI 2: fp32 + bias, store [m][n]
__device__ __forceinline__ int swz4(int row){ return (row ^ (row >> 2)) & 3; }

template<int SPLIT, int EPI>
__global__ __launch_bounds__(256)
void mfma_gemm(const u16* __restrict__ Ahi, const u16* __restrict__ Alo,
               const u16* __restrict__ Bhi, const u16* __restrict__ Blo,
               const float* __restrict__ bias, void* __restrict__ out0, void* __restrict__ out1,
               float scale)
{
  __shared__ __align__(16) u16 Ah[128*32], Bh[128*32], Al[128*32], Bl[128*32];
  const int t = threadIdx.x, lane = t & 63, w = t >> 6;
  const int wr = w >> 1, wc = w & 1;
  const int fr = lane & 15, fk = lane >> 4;
  const int m0 = blockIdx.y * 128, n0 = blockIdx.x * 128;

  f32x4 acc[4][4];
#pragma unroll
  for (int i = 0; i < 4; ++i)
#pragma unroll
    for (int j = 0; j < 4; ++j) acc[i][j] = (f32x4){0.f,0.f,0.f,0.f};

  for (int k0 = 0; k0 < EMBED; k0 += 32){
    __syncthreads();
#pragma unroll
    for (int cc = 0; cc < 2; ++cc){
      int cb = w*128 + cc*64;
      int chunk = cb + lane;
      int row = chunk >> 2, slot = chunk & 3;
      int sl = slot ^ swz4(row);
      stage16(Ahi + (size_t)(m0+row)*EMBED + k0 + sl*8, Ah + cb*8);
      stage16(Bhi + (size_t)(n0+row)*EMBED + k0 + sl*8, Bh + cb*8);
      if (SPLIT == 3){
        stage16(Alo + (size_t)(m0+row)*EMBED + k0 + sl*8, Al + cb*8);
        stage16(Blo + (size_t)(n0+row)*EMBED + k0 + sl*8, Bl + cb*8);
      }
    }
    __syncthreads();

    bf16x8 ah[4], bh[4], al[4], bl[4];
#pragma unroll
    for (int i = 0; i < 4; ++i){
      int ra = wr*64 + i*16 + fr;
      int oa = ra*32 + (fk ^ swz4(ra))*8;
      ah[i] = *(const bf16x8*)&Ah[oa];
      if (SPLIT == 3) al[i] = *(const bf16x8*)&Al[oa];
      int rb = wc*64 + i*16 + fr;
      int ob = rb*32 + (fk ^ swz4(rb))*8;
      bh[i] = *(const bf16x8*)&Bh[ob];
      if (SPLIT == 3) bl[i] = *(const bf16x8*)&Bl[ob];
    }
#pragma unroll
    for (int i = 0; i < 4; ++i)
#pragma unroll
      for (int j = 0; j < 4; ++j){
        acc[i][j] = __builtin_amdgcn_mfma_f32_16x16x32_bf16(ah[i], bh[j], acc[i][j], 0,0,0);
        if (SPLIT == 3){
          acc[i][j] = __builtin_amdgcn_mfma_f32_16x16x32_bf16(ah[i], bl[j], acc[i][j], 0,0,0);
          acc[i][j] = __builtin_amdgcn_mfma_f32_16x16x32_bf16(al[i], bh[j], acc[i][j], 0,0,0);
        }
      }
  }

#pragma unroll
  for (int i = 0; i < 4; ++i)
#pragma unroll
    for (int j = 0; j < 4; ++j)
#pragma unroll
      for (int r = 0; r < 4; ++r){
        int gm = m0 + wr*64 + i*16 + fk*4 + r;   // C row = (lane>>4)*4 + reg
        int gn = n0 + wc*64 + j*16 + fr;         // C col = lane & 15
        float v = acc[i][j][r] * scale;
        if (EPI == 0){
          int b = gm >> 11, tt2 = gm & 2047, h = gn >> 6, d = gn & 63;
          size_t idx = ((size_t)(b*HEADS + h)*TT + tt2)*HDIM + d;
          u16 hi = f2bf(v);
          ((u16*)out0)[idx] = hi;
          ((u16*)out1)[idx] = f2bf(v - bf2f(hi));
        } else if (EPI == 1){
          int b = gm >> 11, tt2 = gm & 2047, h = gn >> 6, d = gn & 63;
          size_t idx = ((size_t)(b*HEADS + h)*HDIM + d)*TT + tt2;
          ((u16*)out0)[idx] = f2bf(v);
        } else {
          ((float*)out0)[(size_t)gm*EMBED + gn] = v + bias[gn];
        }
      }
}

// ---------------- flash attention, MFMA ----------------
// Q,K: [bh][t][64] hi/lo bf16 (Q pre-scaled by 0.125). Vt: [bh][64][t] bf16.
// ctx out: [b][t][h*64+d] bf16.
__global__ __launch_bounds__(256)
void attn_mfma(const u16* __restrict__ Qhi, const u16* __restrict__ Qlo,
               const u16* __restrict__ Khi, const u16* __restrict__ Klo,
               const u16* __restrict__ Vt,  u16* __restrict__ ctx)
{
  __shared__ __align__(16) u16 Qh[64*64], Ql[64*64], Kh[64*64], Kl[64*64], Vs[64*64], Ps[4*16*64];
  const int t = threadIdx.x, lane = t & 63, w = t >> 6;
  const int fr = lane & 15, fk = lane >> 4;
  const int bh = blockIdx.y, q0 = blockIdx.x * 64;
  const size_t kbase = (size_t)bh * TT * HDIM;
  const size_t vbase = (size_t)bh * HDIM * TT;

  // stage Q tiles once (pre-swizzled source, linear LDS dest)
#pragma unroll
  for (int cc = 0; cc < 2; ++cc){
    int cb = w*128 + cc*64;
    int chunk = cb + lane;
    int row = chunk >> 3, slot = chunk & 7;
    int sl = slot ^ (row & 7);
    stage16(Qhi + kbase + (size_t)(q0+row)*HDIM + sl*8, Qh + cb*8);
    stage16(Qlo + kbase + (size_t)(q0+row)*HDIM + sl*8, Ql + cb*8);
  }
  __syncthreads();
  bf16x8 qh[2], ql[2];
#pragma unroll
  for (int ks = 0; ks < 2; ++ks){
    int row = w*16 + fr;
    int off = row*64 + ((ks*4 + fk) ^ (row & 7))*8;
    qh[ks] = *(const bf16x8*)&Qh[off];
    ql[ks] = *(const bf16x8*)&Ql[off];
  }

  float mi[4], li[4];
  f32x4 oacc[4];
#pragma unroll
  for (int r = 0; r < 4; ++r){ mi[r] = -1e30f; li[r] = 0.f; }
#pragma unroll
  for (int n = 0; n < 4; ++n) oacc[n] = (f32x4){0.f,0.f,0.f,0.f};

  for (int kt = 0; kt < TT/64; ++kt){
    int kv0 = kt * 64;
    __syncthreads();
#pragma unroll
    for (int cc = 0; cc < 2; ++cc){
      int cb = w*128 + cc*64;
      int chunk = cb + lane;
      int row = chunk >> 3, slot = chunk & 7;
      int sl = slot ^ (row & 7);
      stage16(Khi + kbase + (size_t)(kv0+row)*HDIM + sl*8, Kh + cb*8);
      stage16(Klo + kbase + (size_t)(kv0+row)*HDIM + sl*8, Kl + cb*8);
      stage16(Vt  + vbase + (size_t)row*TT + kv0 + sl*8,  Vs + cb*8);
    }
    __syncthreads();

    // S = Q K^T (3-MFMA hi/lo)
    f32x4 sacc[4];
#pragma unroll
    for (int n = 0; n < 4; ++n) sacc[n] = (f32x4){0.f,0.f,0.f,0.f};
#pragma unroll
    for (int n = 0; n < 4; ++n)
#pragma unroll
      for (int ks = 0; ks < 2; ++ks){
        int row = n*16 + fr;
        int off = row*64 + ((ks*4 + fk) ^ (row & 7))*8;
        bf16x8 kh = *(const bf16x8*)&Kh[off];
        bf16x8 kl = *(const bf16x8*)&Kl[off];
        sacc[n] = __builtin_amdgcn_mfma_f32_16x16x32_bf16(qh[ks], kh, sacc[n], 0,0,0);
        sacc[n] = __builtin_amdgcn_mfma_f32_16x16x32_bf16(qh[ks], kl, sacc[n], 0,0,0);
        sacc[n] = __builtin_amdgcn_mfma_f32_16x16x32_bf16(ql[ks], kh, sacc[n], 0,0,0);
      }

    // online softmax (rows live in 16-lane groups)
    float scl[4], rsum[4];
#pragma unroll
    for (int r = 0; r < 4; ++r){
      float m = fmaxf(fmaxf(sacc[0][r], sacc[1][r]), fmaxf(sacc[2][r], sacc[3][r]));
#pragma unroll
      for (int off = 1; off < 16; off <<= 1) m = fmaxf(m, __shfl_xor(m, off));
      float mn = fmaxf(mi[r], m);
      scl[r] = __expf(mi[r] - mn);
      mi[r] = mn;
      rsum[r] = 0.f;
    }
#pragma unroll
    for (int n = 0; n < 4; ++n)
#pragma unroll
      for (int r = 0; r < 4; ++r){
        float p = __expf(sacc[n][r] - mi[r]);
        sacc[n][r] = p;
        rsum[r] += p;
      }
#pragma unroll
    for (int r = 0; r < 4; ++r){
#pragma unroll
      for (int off = 1; off < 16; off <<= 1) rsum[r] += __shfl_xor(rsum[r], off);
      li[r] = li[r]*scl[r] + rsum[r];
    }
#pragma unroll
    for (int n = 0; n < 4; ++n)
#pragma unroll
      for (int r = 0; r < 4; ++r) oacc[n][r] *= scl[r];

    // P -> LDS (bf16, swizzled); each wave writes/reads only its own block
#pragma unroll
    for (int n = 0; n < 4; ++n)
#pragma unroll
      for (int r = 0; r < 4; ++r){
        int row = fk*4 + r;
        int col = n*16 + fr;
        int slot = col >> 3;
        Ps[w*1024 + row*64 + (slot ^ (row & 7))*8 + (col & 7)] = f2bf(sacc[n][r]);
      }

    // O += P V
#pragma unroll
    for (int ks = 0; ks < 2; ++ks){
      bf16x8 pa = *(const bf16x8*)&Ps[w*1024 + fr*64 + ((ks*4 + fk) ^ (fr & 7))*8];
#pragma unroll
      for (int n = 0; n < 4; ++n){
        int row = n*16 + fr;
        bf16x8 bv = *(const bf16x8*)&Vs[row*64 + ((ks*4 + fk) ^ (row & 7))*8];
        oacc[n] = __builtin_amdgcn_mfma_f32_16x16x32_bf16(pa, bv, oacc[n], 0,0,0);
      }
    }
  }

  int b = bh >> 4, h = bh & 15;
#pragma unroll
  for (int r = 0; r < 4; ++r){
    float inv = 1.f / li[r];
    int q = q0 + w*16 + fk*4 + r;
#pragma unroll
    for (int n = 0; n < 4; ++n){
      int d = n*16 + fr;
      ctx[((size_t)(b*TT + q))*EMBED + h*HDIM + d] = f2bf(oacc[n][r]*inv);
    }
  }
}

// ---------------- launch ----------------
extern "C" void kernel_launch(void* const* d_in, const int* in_sizes, int n_in,
                              void* d_out, int out_size, void* d_ws, size_t ws_size,
                              hipStream_t stream) {
  const float* x  = (const float*)d_in[0];
  const float* Wq = (const float*)d_in[1];
  const float* Aq = (const float*)d_in[2];
  const float* Bq = (const float*)d_in[3];
  const float* Wk = (const float*)d_in[4];
  const float* Ak = (const float*)d_in[5];
  const float* Bk = (const float*)d_in[6];
  const float* Wv = (const float*)d_in[7];
  const float* Av = (const float*)d_in[8];
  const float* Bv = (const float*)d_in[9];
  const float* Wo = (const float*)d_in[10];
  const float* bo = (const float*)d_in[11];
  float* out = (float*)d_out;

  char* ws = (char*)d_ws;
  const size_t MB = 1u << 20;
  u16* xhi  = (u16*)(ws + 0*MB);
  u16* xlo  = (u16*)(ws + 8*MB);
  u16* whiq = (u16*)(ws + 16*MB);
  u16* wloq = (u16*)(ws + 18*MB);
  u16* whik = (u16*)(ws + 20*MB);
  u16* wlok = (u16*)(ws + 22*MB);
  u16* wv   = (u16*)(ws + 24*MB);
  u16* wob  = (u16*)(ws + 26*MB);
  u16* qhi  = (u16*)(ws + 28*MB);
  u16* qlo  = (u16*)(ws + 36*MB);
  u16* khi  = (u16*)(ws + 44*MB);
  u16* klo  = (u16*)(ws + 52*MB);
  u16* vt   = (u16*)(ws + 60*MB);
  u16* ctx  = (u16*)(ws + 68*MB);   // total 76 MB

  dim3 blk(256);
  split_x_kernel<<<dim3(MTOT*EMBED/256), blk, 0, stream>>>(x, xhi, xlo);
  weff_split_kernel<<<dim3(4096), blk, 0, stream>>>(Wq, Aq, Bq, whiq, wloq);
  weff_split_kernel<<<dim3(4096), blk, 0, stream>>>(Wk, Ak, Bk, whik, wlok);
  weff_bf16_kernel<<<dim3(4096), blk, 0, stream>>>(Wv, Av, Bv, wv);
  bf16_cast_kernel<<<dim3(4096), blk, 0, stream>>>(Wo, wob);

  dim3 ggrid(EMBED/128, MTOT/128);
  mfma_gemm<3,0><<<ggrid, blk, 0, stream>>>(xhi, xlo, whiq, wloq, nullptr, qhi, qlo, 0.125f);
  mfma_gemm<3,0><<<ggrid, blk, 0, stream>>>(xhi, xlo, whik, wlok, nullptr, khi, klo, 1.0f);
  mfma_gemm<1,1><<<ggrid, blk, 0, stream>>>(xhi, nullptr, wv, nullptr, nullptr, vt, nullptr, 1.0f);

  dim3 agrid(TT/64, BH);
  attn_mfma<<<agrid, blk, 0, stream>>>(qhi, qlo, khi, klo, vt, ctx);

  mfma_gemm<1,2><<<ggrid, blk, 0, stream>>>(ctx, nullptr, wob, nullptr, bo, out, nullptr, 1.0f);
}

// Round 5
// 337.479 us; speedup vs baseline: 7.0094x; 1.2302x over previous
//
#include <hip/hip_runtime.h>
#include <hip/hip_bf16.h>
#include <math.h>

#define EMBED 1024
#define HEADS 16
#define HDIM 64
#define RANK 8
#define BB 2
#define TT 2048
#define MTOT (BB*TT)
#define BH (BB*HEADS)

typedef __attribute__((ext_vector_type(8))) short bf16x8;
typedef __attribute__((ext_vector_type(4))) float f32x4;
typedef unsigned short u16;

__device__ __forceinline__ u16 f2bf(float f){
  unsigned u = __float_as_uint(f);
  u += 0x7FFF + ((u >> 16) & 1);          // RNE
  return (u16)(u >> 16);
}
__device__ __forceinline__ float bf2f(u16 h){ return __uint_as_float(((unsigned)h) << 16); }

__device__ __forceinline__ void stage16(const void* g, void* l){
  __builtin_amdgcn_global_load_lds((const __attribute__((address_space(1))) unsigned int*)g,
                                   (__attribute__((address_space(3))) unsigned int*)l, 16, 0, 0);
}

// ---------------- prep kernels ----------------
__global__ void split_x_kernel(const float* __restrict__ x, u16* __restrict__ xhi, u16* __restrict__ xlo){
  int i = blockIdx.x * 256 + threadIdx.x;           // 4M
  float v = x[i];
  u16 h = f2bf(v);
  xhi[i] = h;
  xlo[i] = f2bf(v - bf2f(h));
}

__global__ void weff_split_kernel(const float* __restrict__ W, const float* __restrict__ A,
                                  const float* __restrict__ Bm,
                                  u16* __restrict__ whi, u16* __restrict__ wlo){
  int i = blockIdx.x * 256 + threadIdx.x;           // 1M, i = o*1024+c
  int o = i >> 10, c = i & 1023;
  float s = 0.f;
#pragma unroll
  for (int r = 0; r < RANK; ++r) s += A[c*RANK+r] * Bm[r*EMBED+o];
  float v = W[i] + 2.0f * s;
  u16 h = f2bf(v);
  whi[i] = h;
  wlo[i] = f2bf(v - bf2f(h));
}

__global__ void bf16_cast_kernel(const float* __restrict__ W, u16* __restrict__ wb){
  int i = blockIdx.x * 256 + threadIdx.x;
  wb[i] = f2bf(W[i]);
}

__device__ __forceinline__ int swz4(int row){ return (row ^ (row >> 2)) & 3; }

// ---------------- fused QKV projection GEMM ----------------
// A = x (hi/lo) [4096][1024]; B = concat [Wq;Wk;Wv] (hi/lo) [3072][1024].
// Q/K blocks (n0<2048): 3-MFMA hi/lo, split-store [bh][t][d].
// V blocks: 1-MFMA, bf16 store V^T [bh][d][t].
__global__ __launch_bounds__(256)
void qkv_gemm(const u16* __restrict__ Ahi, const u16* __restrict__ Alo,
              const u16* __restrict__ Bhi, const u16* __restrict__ Blo,
              u16* __restrict__ qhi, u16* __restrict__ qlo,
              u16* __restrict__ khi, u16* __restrict__ klo,
              u16* __restrict__ vt)
{
  __shared__ __align__(16) u16 Ah[128*32], Bh[128*32], Al[128*32], Bl[128*32];
  const int t = threadIdx.x, lane = t & 63, w = t >> 6;
  const int wr = w >> 1, wc = w & 1;
  const int fr = lane & 15, fk = lane >> 4;
  const int m0 = blockIdx.y * 128, n0 = blockIdx.x * 128;
  const bool full = (n0 < 2048);

  f32x4 acc[4][4];
#pragma unroll
  for (int i = 0; i < 4; ++i)
#pragma unroll
    for (int j = 0; j < 4; ++j) acc[i][j] = (f32x4){0.f,0.f,0.f,0.f};

  for (int k0 = 0; k0 < EMBED; k0 += 32){
    __syncthreads();
#pragma unroll
    for (int cc = 0; cc < 2; ++cc){
      int cb = w*128 + cc*64;
      int chunk = cb + lane;
      int row = chunk >> 2, slot = chunk & 3;
      int sl = slot ^ swz4(row);
      stage16(Ahi + (size_t)(m0+row)*EMBED + k0 + sl*8, Ah + cb*8);
      stage16(Bhi + (size_t)(n0+row)*EMBED + k0 + sl*8, Bh + cb*8);
      if (full){
        stage16(Alo + (size_t)(m0+row)*EMBED + k0 + sl*8, Al + cb*8);
        stage16(Blo + (size_t)(n0+row)*EMBED + k0 + sl*8, Bl + cb*8);
      }
    }
    __syncthreads();

    bf16x8 ah[4], bh[4], al[4], bl[4];
#pragma unroll
    for (int i = 0; i < 4; ++i){
      int ra = wr*64 + i*16 + fr;
      int oa = ra*32 + (fk ^ swz4(ra))*8;
      ah[i] = *(const bf16x8*)&Ah[oa];
      if (full) al[i] = *(const bf16x8*)&Al[oa];
      int rb = wc*64 + i*16 + fr;
      int ob = rb*32 + (fk ^ swz4(rb))*8;
      bh[i] = *(const bf16x8*)&Bh[ob];
      if (full) bl[i] = *(const bf16x8*)&Bl[ob];
    }
#pragma unroll
    for (int i = 0; i < 4; ++i)
#pragma unroll
      for (int j = 0; j < 4; ++j){
        acc[i][j] = __builtin_amdgcn_mfma_f32_16x16x32_bf16(ah[i], bh[j], acc[i][j], 0,0,0);
        if (full){
          acc[i][j] = __builtin_amdgcn_mfma_f32_16x16x32_bf16(ah[i], bl[j], acc[i][j], 0,0,0);
          acc[i][j] = __builtin_amdgcn_mfma_f32_16x16x32_bf16(al[i], bh[j], acc[i][j], 0,0,0);
        }
      }
  }

  const int mat = (n0 + wc*64) >> 10;        // 0=Q 1=K 2=V (uniform per wave)
#pragma unroll
  for (int i = 0; i < 4; ++i)
#pragma unroll
    for (int j = 0; j < 4; ++j)
#pragma unroll
      for (int r = 0; r < 4; ++r){
        int gm = m0 + wr*64 + i*16 + fk*4 + r;
        int gn = n0 + wc*64 + j*16 + fr;
        int col = gn & 1023;
        float v = acc[i][j][r];
        int b = gm >> 11, tt2 = gm & 2047, h = col >> 6, d = col & 63;
        if (mat == 2){
          vt[((size_t)(b*HEADS + h)*HDIM + d)*TT + tt2] = f2bf(v);
        } else {
          if (mat == 0) v *= 0.125f;
          size_t idx = ((size_t)(b*HEADS + h)*TT + tt2)*HDIM + d;
          u16 hi = f2bf(v);
          u16 lo = f2bf(v - bf2f(hi));
          if (mat == 0){ qhi[idx] = hi; qlo[idx] = lo; }
          else         { khi[idx] = hi; klo[idx] = lo; }
        }
      }
}

// ---------------- flash attention, MFMA ----------------
// Q,K: [bh][t][64] hi/lo bf16 (Q pre-scaled). Vt: [bh][64][t] bf16.
// LDS 32 KB: Q-staging aliased over K buffers (Q lives in regs after prologue).
__global__ __launch_bounds__(256)
void attn_mfma(const u16* __restrict__ Qhi, const u16* __restrict__ Qlo,
               const u16* __restrict__ Khi, const u16* __restrict__ Klo,
               const u16* __restrict__ Vt,  u16* __restrict__ ctx)
{
  __shared__ __align__(16) u16 smem[16384];   // 32 KB
  u16* Kh = smem;            // 4096 (aliases Qh staging)
  u16* Kl = smem + 4096;     // 4096 (aliases Ql staging)
  u16* Vs = smem + 8192;     // 4096
  u16* Ps = smem + 12288;    // 4096 (4 waves x 1024)
  const int t = threadIdx.x, lane = t & 63, w = t >> 6;
  const int fr = lane & 15, fk = lane >> 4;
  const int bh = blockIdx.y, q0 = blockIdx.x * 64;
  const size_t kbase = (size_t)bh * TT * HDIM;
  const size_t vbase = (size_t)bh * HDIM * TT;

  // stage Q (into K region), pull to registers
#pragma unroll
  for (int cc = 0; cc < 2; ++cc){
    int cb = w*128 + cc*64;
    int chunk = cb + lane;
    int row = chunk >> 3, slot = chunk & 7;
    int sl = slot ^ (row & 7);
    stage16(Qhi + kbase + (size_t)(q0+row)*HDIM + sl*8, Kh + cb*8);
    stage16(Qlo + kbase + (size_t)(q0+row)*HDIM + sl*8, Kl + cb*8);
  }
  __syncthreads();
  bf16x8 qh[2], ql[2];
#pragma unroll
  for (int ks = 0; ks < 2; ++ks){
    int row = w*16 + fr;
    int off = row*64 + ((ks*4 + fk) ^ (row & 7))*8;
    qh[ks] = *(const bf16x8*)&Kh[off];
    ql[ks] = *(const bf16x8*)&Kl[off];
  }

  float mi[4], li[4];
  f32x4 oacc[4];
#pragma unroll
  for (int r = 0; r < 4; ++r){ mi[r] = -1e30f; li[r] = 0.f; }
#pragma unroll
  for (int n = 0; n < 4; ++n) oacc[n] = (f32x4){0.f,0.f,0.f,0.f};

  for (int kt = 0; kt < TT/64; ++kt){
    int kv0 = kt * 64;
    __syncthreads();   // K/V buffers free (first iter: q reg-loads drained)
#pragma unroll
    for (int cc = 0; cc < 2; ++cc){
      int cb = w*128 + cc*64;
      int chunk = cb + lane;
      int row = chunk >> 3, slot = chunk & 7;
      int sl = slot ^ (row & 7);
      stage16(Khi + kbase + (size_t)(kv0+row)*HDIM + sl*8, Kh + cb*8);
      stage16(Klo + kbase + (size_t)(kv0+row)*HDIM + sl*8, Kl + cb*8);
      stage16(Vt  + vbase + (size_t)row*TT + kv0 + sl*8,  Vs + cb*8);
    }
    __syncthreads();

    // S = Q K^T (3-MFMA hi/lo)
    f32x4 sacc[4];
#pragma unroll
    for (int n = 0; n < 4; ++n) sacc[n] = (f32x4){0.f,0.f,0.f,0.f};
#pragma unroll
    for (int n = 0; n < 4; ++n)
#pragma unroll
      for (int ks = 0; ks < 2; ++ks){
        int row = n*16 + fr;
        int off = row*64 + ((ks*4 + fk) ^ (row & 7))*8;
        bf16x8 kh = *(const bf16x8*)&Kh[off];
        bf16x8 kl = *(const bf16x8*)&Kl[off];
        sacc[n] = __builtin_amdgcn_mfma_f32_16x16x32_bf16(qh[ks], kh, sacc[n], 0,0,0);
        sacc[n] = __builtin_amdgcn_mfma_f32_16x16x32_bf16(qh[ks], kl, sacc[n], 0,0,0);
        sacc[n] = __builtin_amdgcn_mfma_f32_16x16x32_bf16(ql[ks], kh, sacc[n], 0,0,0);
      }

    // tile max per row
    float mt[4];
#pragma unroll
    for (int r = 0; r < 4; ++r){
      float m = fmaxf(fmaxf(sacc[0][r], sacc[1][r]), fmaxf(sacc[2][r], sacc[3][r]));
#pragma unroll
      for (int off = 1; off < 16; off <<= 1) m = fmaxf(m, __shfl_xor(m, off));
      mt[r] = m;
    }
    // defer-max: skip rescale when growth <= 8 for all rows in wave
    bool dfr = true;
#pragma unroll
    for (int r = 0; r < 4; ++r) dfr = dfr && (mt[r] - mi[r] <= 8.0f);
    if (!__all(dfr)){
#pragma unroll
      for (int r = 0; r < 4; ++r){
        float mn = fmaxf(mi[r], mt[r]);
        float sc = __expf(mi[r] - mn);
        mi[r] = mn;
        li[r] *= sc;
#pragma unroll
        for (int n = 0; n < 4; ++n) oacc[n][r] *= sc;
      }
    }
    // P = exp(S - mi), row sums
    float rsum[4] = {0.f,0.f,0.f,0.f};
#pragma unroll
    for (int n = 0; n < 4; ++n)
#pragma unroll
      for (int r = 0; r < 4; ++r){
        float p = __expf(sacc[n][r] - mi[r]);
        sacc[n][r] = p;
        rsum[r] += p;
      }
#pragma unroll
    for (int r = 0; r < 4; ++r){
#pragma unroll
      for (int off = 1; off < 16; off <<= 1) rsum[r] += __shfl_xor(rsum[r], off);
      li[r] += rsum[r];
    }

    // P -> LDS (bf16, swizzled), per-wave region
#pragma unroll
    for (int n = 0; n < 4; ++n)
#pragma unroll
      for (int r = 0; r < 4; ++r){
        int row = fk*4 + r;
        int col = n*16 + fr;
        int slot = col >> 3;
        Ps[w*1024 + row*64 + (slot ^ (row & 7))*8 + (col & 7)] = f2bf(sacc[n][r]);
      }

    // O += P V
#pragma unroll
    for (int ks = 0; ks < 2; ++ks){
      bf16x8 pa = *(const bf16x8*)&Ps[w*1024 + fr*64 + ((ks*4 + fk) ^ (fr & 7))*8];
#pragma unroll
      for (int n = 0; n < 4; ++n){
        int row = n*16 + fr;
        bf16x8 bv = *(const bf16x8*)&Vs[row*64 + ((ks*4 + fk) ^ (row & 7))*8];
        oacc[n] = __builtin_amdgcn_mfma_f32_16x16x32_bf16(pa, bv, oacc[n], 0,0,0);
      }
    }
  }

  int b = bh >> 4, h = bh & 15;
#pragma unroll
  for (int r = 0; r < 4; ++r){
    float inv = 1.f / li[r];
    int q = q0 + w*16 + fk*4 + r;
#pragma unroll
    for (int n = 0; n < 4; ++n){
      int d = n*16 + fr;
      ctx[((size_t)(b*TT + q))*EMBED + h*HDIM + d] = f2bf(oacc[n][r]*inv);
    }
  }
}

// ---------------- output projection (bf16 MFMA, fp32 + bias out) ----------------
__global__ __launch_bounds__(256)
void outproj_gemm(const u16* __restrict__ Ab, const u16* __restrict__ Bb,
                  const float* __restrict__ bias, float* __restrict__ C)
{
  __shared__ __align__(16) u16 Ah[128*32], Bh[128*32];
  const int t = threadIdx.x, lane = t & 63, w = t >> 6;
  const int wr = w >> 1, wc = w & 1;
  const int fr = lane & 15, fk = lane >> 4;
  const int m0 = blockIdx.y * 128, n0 = blockIdx.x * 128;

  f32x4 acc[4][4];
#pragma unroll
  for (int i = 0; i < 4; ++i)
#pragma unroll
    for (int j = 0; j < 4; ++j) acc[i][j] = (f32x4){0.f,0.f,0.f,0.f};

  for (int k0 = 0; k0 < EMBED; k0 += 32){
    __syncthreads();
#pragma unroll
    for (int cc = 0; cc < 2; ++cc){
      int cb = w*128 + cc*64;
      int chunk = cb + lane;
      int row = chunk >> 2, slot = chunk & 3;
      int sl = slot ^ swz4(row);
      stage16(Ab + (size_t)(m0+row)*EMBED + k0 + sl*8, Ah + cb*8);
      stage16(Bb + (size_t)(n0+row)*EMBED + k0 + sl*8, Bh + cb*8);
    }
    __syncthreads();

    bf16x8 ah[4], bh[4];
#pragma unroll
    for (int i = 0; i < 4; ++i){
      int ra = wr*64 + i*16 + fr;
      ah[i] = *(const bf16x8*)&Ah[ra*32 + (fk ^ swz4(ra))*8];
      int rb = wc*64 + i*16 + fr;
      bh[i] = *(const bf16x8*)&Bh[rb*32 + (fk ^ swz4(rb))*8];
    }
#pragma unroll
    for (int i = 0; i < 4; ++i)
#pragma unroll
      for (int j = 0; j < 4; ++j)
        acc[i][j] = __builtin_amdgcn_mfma_f32_16x16x32_bf16(ah[i], bh[j], acc[i][j], 0,0,0);
  }

#pragma unroll
  for (int i = 0; i < 4; ++i)
#pragma unroll
    for (int j = 0; j < 4; ++j)
#pragma unroll
      for (int r = 0; r < 4; ++r){
        int gm = m0 + wr*64 + i*16 + fk*4 + r;
        int gn = n0 + wc*64 + j*16 + fr;
        C[(size_t)gm*EMBED + gn] = acc[i][j][r] + bias[gn];
      }
}

// ---------------- launch ----------------
extern "C" void kernel_launch(void* const* d_in, const int* in_sizes, int n_in,
                              void* d_out, int out_size, void* d_ws, size_t ws_size,
                              hipStream_t stream) {
  const float* x  = (const float*)d_in[0];
  const float* Wq = (const float*)d_in[1];
  const float* Aq = (const float*)d_in[2];
  const float* Bq = (const float*)d_in[3];
  const float* Wk = (const float*)d_in[4];
  const float* Ak = (const float*)d_in[5];
  const float* Bk = (const float*)d_in[6];
  const float* Wv = (const float*)d_in[7];
  const float* Av = (const float*)d_in[8];
  const float* Bv = (const float*)d_in[9];
  const float* Wo = (const float*)d_in[10];
  const float* bo = (const float*)d_in[11];
  float* out = (float*)d_out;

  char* ws = (char*)d_ws;
  const size_t MB = 1u << 20;
  u16* xhi  = (u16*)(ws + 0*MB);    // 8 MB (aliased by ctx later)
  u16* xlo  = (u16*)(ws + 8*MB);    // 8 MB
  u16* whi  = (u16*)(ws + 16*MB);   // 6 MB  [Wq;Wk;Wv] hi
  u16* wlo  = (u16*)(ws + 22*MB);   // 6 MB
  u16* wob  = (u16*)(ws + 28*MB);   // 2 MB
  u16* qhi  = (u16*)(ws + 30*MB);   // 8 MB
  u16* qlo  = (u16*)(ws + 38*MB);   // 8 MB
  u16* khi  = (u16*)(ws + 46*MB);   // 8 MB
  u16* klo  = (u16*)(ws + 54*MB);   // 8 MB
  u16* vt   = (u16*)(ws + 62*MB);   // 8 MB
  u16* ctx  = (u16*)(ws + 0*MB);    // 8 MB, over xhi (dead after qkv_gemm)

  dim3 blk(256);
  split_x_kernel<<<dim3(MTOT*EMBED/256), blk, 0, stream>>>(x, xhi, xlo);
  weff_split_kernel<<<dim3(4096), blk, 0, stream>>>(Wq, Aq, Bq, whi,           wlo);
  weff_split_kernel<<<dim3(4096), blk, 0, stream>>>(Wk, Ak, Bk, whi + 1048576, wlo + 1048576);
  weff_split_kernel<<<dim3(4096), blk, 0, stream>>>(Wv, Av, Bv, whi + 2097152, wlo + 2097152);
  bf16_cast_kernel<<<dim3(4096), blk, 0, stream>>>(Wo, wob);

  qkv_gemm<<<dim3(3*EMBED/128, MTOT/128), blk, 0, stream>>>(xhi, xlo, whi, wlo,
                                                            qhi, qlo, khi, klo, vt);

  attn_mfma<<<dim3(TT/64, BH), blk, 0, stream>>>(qhi, qlo, khi, klo, vt, ctx);

  outproj_gemm<<<dim3(EMBED/128, MTOT/128), blk, 0, stream>>>(ctx, wob, bo, out);
}

// Round 8
// 302.670 us; speedup vs baseline: 7.8155x; 1.1150x over previous
//
#include <hip/hip_runtime.h>
#include <hip/hip_bf16.h>
#include <math.h>

#define EMBED 1024
#define HEADS 16
#define HDIM 64
#define RANK 8
#define BB 2
#define TT 2048
#define MTOT (BB*TT)
#define BH (BB*HEADS)

typedef __attribute__((ext_vector_type(8))) short bf16x8;
typedef __attribute__((ext_vector_type(4))) float f32x4;
typedef unsigned short u16;
typedef unsigned int u32;

__device__ __forceinline__ u16 f2bf(float f){
  unsigned u = __float_as_uint(f);
  u += 0x7FFF + ((u >> 16) & 1);          // RNE
  return (u16)(u >> 16);
}
__device__ __forceinline__ float bf2f(u16 h){ return __uint_as_float(((unsigned)h) << 16); }

__device__ __forceinline__ u32 cvtpk(float lo, float hi){
  u32 r;
  asm("v_cvt_pk_bf16_f32 %0, %1, %2" : "=v"(r) : "v"(lo), "v"(hi));
  return r;
}

__device__ __forceinline__ void stage16(const void* g, void* l){
  __builtin_amdgcn_global_load_lds((const __attribute__((address_space(1))) unsigned int*)g,
                                   (__attribute__((address_space(3))) unsigned int*)l, 16, 0, 0);
}

// ---------------- prep kernels ----------------
__global__ void split_x_kernel(const float* __restrict__ x, u16* __restrict__ xhi, u16* __restrict__ xlo){
  int i = blockIdx.x * 256 + threadIdx.x;           // 4M
  float v = x[i];
  u16 h = f2bf(v);
  xhi[i] = h;
  xlo[i] = f2bf(v - bf2f(h));
}

// y = 0,1,2 : W_eff hi/lo split for Q/K/V.  y = 3 : plain bf16 cast of Wo.
__global__ void prep_weights_kernel(const float* __restrict__ W0, const float* __restrict__ W1,
                                    const float* __restrict__ W2, const float* __restrict__ W3,
                                    const float* __restrict__ A0, const float* __restrict__ A1,
                                    const float* __restrict__ A2,
                                    const float* __restrict__ B0, const float* __restrict__ B1,
                                    const float* __restrict__ B2,
                                    u16* __restrict__ whi, u16* __restrict__ wlo,
                                    u16* __restrict__ wob){
  int i = blockIdx.x * 256 + threadIdx.x;           // 1M per y
  int y = blockIdx.y;
  if (y == 3){ wob[i] = f2bf(W3[i]); return; }
  const float* W = (y == 0) ? W0 : (y == 1) ? W1 : W2;
  const float* A = (y == 0) ? A0 : (y == 1) ? A1 : A2;
  const float* Bm = (y == 0) ? B0 : (y == 1) ? B1 : B2;
  int o = i >> 10, c = i & 1023;
  float s = 0.f;
#pragma unroll
  for (int r = 0; r < RANK; ++r) s += A[c*RANK+r] * Bm[r*EMBED+o];
  float v = W[i] + 2.0f * s;
  u16 h = f2bf(v);
  size_t off = (size_t)y * 1048576 + i;
  whi[off] = h;
  wlo[off] = f2bf(v - bf2f(h));
}

__device__ __forceinline__ int swz4(int row){ return (row ^ (row >> 2)) & 3; }

// ---------------- fused QKV projection GEMM ----------------
__global__ __launch_bounds__(256)
void qkv_gemm(const u16* __restrict__ Ahi, const u16* __restrict__ Alo,
              const u16* __restrict__ Bhi, const u16* __restrict__ Blo,
              u16* __restrict__ qhi, u16* __restrict__ qlo,
              u16* __restrict__ khi, u16* __restrict__ klo,
              u16* __restrict__ vt)
{
  __shared__ __align__(16) u16 Ah[128*32], Bh[128*32], Al[128*32], Bl[128*32];
  const int t = threadIdx.x, lane = t & 63, w = t >> 6;
  const int wr = w >> 1, wc = w & 1;
  const int fr = lane & 15, fk = lane >> 4;
  const int m0 = blockIdx.y * 128, n0 = blockIdx.x * 128;
  const bool full = (n0 < 2048);

  f32x4 acc[4][4];
#pragma unroll
  for (int i = 0; i < 4; ++i)
#pragma unroll
    for (int j = 0; j < 4; ++j) acc[i][j] = (f32x4){0.f,0.f,0.f,0.f};

  for (int k0 = 0; k0 < EMBED; k0 += 32){
    __syncthreads();
#pragma unroll
    for (int cc = 0; cc < 2; ++cc){
      int cb = w*128 + cc*64;
      int chunk = cb + lane;
      int row = chunk >> 2, slot = chunk & 3;
      int sl = slot ^ swz4(row);
      stage16(Ahi + (size_t)(m0+row)*EMBED + k0 + sl*8, Ah + cb*8);
      stage16(Bhi + (size_t)(n0+row)*EMBED + k0 + sl*8, Bh + cb*8);
      if (full){
        stage16(Alo + (size_t)(m0+row)*EMBED + k0 + sl*8, Al + cb*8);
        stage16(Blo + (size_t)(n0+row)*EMBED + k0 + sl*8, Bl + cb*8);
      }
    }
    __syncthreads();

    bf16x8 ah[4], bh[4], al[4], bl[4];
#pragma unroll
    for (int i = 0; i < 4; ++i){
      int ra = wr*64 + i*16 + fr;
      int oa = ra*32 + (fk ^ swz4(ra))*8;
      ah[i] = *(const bf16x8*)&Ah[oa];
      if (full) al[i] = *(const bf16x8*)&Al[oa];
      int rb = wc*64 + i*16 + fr;
      int ob = rb*32 + (fk ^ swz4(rb))*8;
      bh[i] = *(const bf16x8*)&Bh[ob];
      if (full) bl[i] = *(const bf16x8*)&Bl[ob];
    }
#pragma unroll
    for (int i = 0; i < 4; ++i)
#pragma unroll
      for (int j = 0; j < 4; ++j){
        acc[i][j] = __builtin_amdgcn_mfma_f32_16x16x32_bf16(ah[i], bh[j], acc[i][j], 0,0,0);
        if (full){
          acc[i][j] = __builtin_amdgcn_mfma_f32_16x16x32_bf16(ah[i], bl[j], acc[i][j], 0,0,0);
          acc[i][j] = __builtin_amdgcn_mfma_f32_16x16x32_bf16(al[i], bh[j], acc[i][j], 0,0,0);
        }
      }
  }

  const int mat = (n0 + wc*64) >> 10;        // 0=Q 1=K 2=V (uniform per wave)
  const float QSCALE = 0.125f * 1.44269504089f;   // fold 1/sqrt(64) and log2(e)
#pragma unroll
  for (int i = 0; i < 4; ++i)
#pragma unroll
    for (int j = 0; j < 4; ++j)
#pragma unroll
      for (int r = 0; r < 4; ++r){
        int gm = m0 + wr*64 + i*16 + fk*4 + r;
        int gn = n0 + wc*64 + j*16 + fr;
        int col = gn & 1023;
        float v = acc[i][j][r];
        int b = gm >> 11, tt2 = gm & 2047, h = col >> 6, d = col & 63;
        if (mat == 2){
          vt[((size_t)(b*HEADS + h)*HDIM + d)*TT + tt2] = f2bf(v);
        } else {
          if (mat == 0) v *= QSCALE;
          size_t idx = ((size_t)(b*HEADS + h)*TT + tt2)*HDIM + d;
          u16 hi = f2bf(v);
          u16 lo = f2bf(v - bf2f(hi));
          if (mat == 0){ qhi[idx] = hi; qlo[idx] = lo; }
          else         { khi[idx] = hi; klo[idx] = lo; }
        }
      }
}

// ---------------- flash attention, MFMA, swapped QK^T ----------------
// S^T = K Q^T via mfma(Kfrag, Qfrag): rows=kv=(fk*4+r), cols=q=fr.
// Per-lane softmax state for q-row fr. Logits in log2 units (Q pre-scaled by log2e/8).
__global__ __launch_bounds__(256)
void attn_mfma(const u16* __restrict__ Qhi, const u16* __restrict__ Qlo,
               const u16* __restrict__ Khi, const u16* __restrict__ Klo,
               const u16* __restrict__ Vt,  u16* __restrict__ ctx)
{
  __shared__ __align__(16) u16 smem[16384];   // 32 KB
  u16* Kh = smem;            // 4096 (aliases Q staging)
  u16* Kl = smem + 4096;     // 4096
  u16* Vs = smem + 8192;     // 4096
  u16* Ps = smem + 12288;    // 4096 (4 waves x 1024)
  const int t = threadIdx.x, lane = t & 63, w = t >> 6;
  const int fr = lane & 15, fk = lane >> 4;
  const int bh = blockIdx.y, q0 = blockIdx.x * 64;
  const size_t kbase = (size_t)bh * TT * HDIM;
  const size_t vbase = (size_t)bh * HDIM * TT;

  // stage Q (into K region), pull to registers
#pragma unroll
  for (int cc = 0; cc < 2; ++cc){
    int cb = w*128 + cc*64;
    int chunk = cb + lane;
    int row = chunk >> 3, slot = chunk & 7;
    int sl = slot ^ (row & 7);
    stage16(Qhi + kbase + (size_t)(q0+row)*HDIM + sl*8, Kh + cb*8);
    stage16(Qlo + kbase + (size_t)(q0+row)*HDIM + sl*8, Kl + cb*8);
  }
  __syncthreads();
  bf16x8 qh[2], ql[2];
#pragma unroll
  for (int ks = 0; ks < 2; ++ks){
    int row = w*16 + fr;
    int off = row*64 + ((ks*4 + fk) ^ (row & 7))*8;
    qh[ks] = *(const bf16x8*)&Kh[off];
    ql[ks] = *(const bf16x8*)&Kl[off];
  }

  float mi = -1e30f, li = 0.f;
  f32x4 oacc[4];
#pragma unroll
  for (int n = 0; n < 4; ++n) oacc[n] = (f32x4){0.f,0.f,0.f,0.f};

  for (int kt = 0; kt < TT/64; ++kt){
    int kv0 = kt * 64;
    __syncthreads();   // K/V buffers free (first iter: q reg-loads drained)
#pragma unroll
    for (int cc = 0; cc < 2; ++cc){
      int cb = w*128 + cc*64;
      int chunk = cb + lane;
      int row = chunk >> 3, slot = chunk & 7;
      int sl = slot ^ (row & 7);
      stage16(Khi + kbase + (size_t)(kv0+row)*HDIM + sl*8, Kh + cb*8);
      stage16(Klo + kbase + (size_t)(kv0+row)*HDIM + sl*8, Kl + cb*8);
      stage16(Vt  + vbase + (size_t)row*TT + kv0 + sl*8,  Vs + cb*8);
    }
    __syncthreads();

    // S^T = K Q^T (3-MFMA hi/lo), rows=kv, cols=q=fr
    f32x4 sacc[4];
#pragma unroll
    for (int n = 0; n < 4; ++n) sacc[n] = (f32x4){0.f,0.f,0.f,0.f};
#pragma unroll
    for (int n = 0; n < 4; ++n)
#pragma unroll
      for (int ks = 0; ks < 2; ++ks){
        int row = n*16 + fr;
        int off = row*64 + ((ks*4 + fk) ^ (row & 7))*8;
        bf16x8 kh = *(const bf16x8*)&Kh[off];
        bf16x8 kl = *(const bf16x8*)&Kl[off];
        sacc[n] = __builtin_amdgcn_mfma_f32_16x16x32_bf16(kh, qh[ks], sacc[n], 0,0,0);
        sacc[n] = __builtin_amdgcn_mfma_f32_16x16x32_bf16(kl, qh[ks], sacc[n], 0,0,0);
        sacc[n] = __builtin_amdgcn_mfma_f32_16x16x32_bf16(kh, ql[ks], sacc[n], 0,0,0);
      }

    // per-lane tile max over this lane's 16 values, then across the 4 fk-groups
    float mt = fmaxf(fmaxf(sacc[0][0], sacc[0][1]), fmaxf(sacc[0][2], sacc[0][3]));
#pragma unroll
    for (int n = 1; n < 4; ++n)
      mt = fmaxf(mt, fmaxf(fmaxf(sacc[n][0], sacc[n][1]), fmaxf(sacc[n][2], sacc[n][3])));
    mt = fmaxf(mt, __shfl_xor(mt, 16));
    mt = fmaxf(mt, __shfl_xor(mt, 32));

    // defer-max (log2 units; 11.54 ~ e^8)
    if (__any(mt > mi + 11.54f)){
      float mn = fmaxf(mi, mt);
      float sc = exp2f(mi - mn);
      mi = mn;
      li *= sc;
      float sct[4];
#pragma unroll
      for (int r = 0; r < 4; ++r) sct[r] = __shfl(sc, fk*4 + r);
#pragma unroll
      for (int n = 0; n < 4; ++n)
#pragma unroll
        for (int r = 0; r < 4; ++r) oacc[n][r] *= sct[r];
    }

    // P = exp2(S - mi), in-lane sum + 2 shuffles
    float rs = 0.f;
#pragma unroll
    for (int n = 0; n < 4; ++n)
#pragma unroll
      for (int r = 0; r < 4; ++r){
        float p = exp2f(sacc[n][r] - mi);
        sacc[n][r] = p;
        rs += p;
      }
    rs += __shfl_xor(rs, 16);
    rs += __shfl_xor(rs, 32);
    li += rs;

    // pack P (bf16 pairs) and write 4x ds_write_b64 into row q=fr
#pragma unroll
    for (int n = 0; n < 4; ++n){
      u32 u0 = cvtpk(sacc[n][0], sacc[n][1]);
      u32 u1 = cvtpk(sacc[n][2], sacc[n][3]);
      int slot = n*2 + (fk >> 1);
      int idx = w*1024 + fr*64 + (slot ^ (fr & 7))*8 + (fk & 1)*4;
      uint2 pk; pk.x = u0; pk.y = u1;
      *(uint2*)&Ps[idx] = pk;
    }

    // O += P V  (pa rows=q=fr -> output rows (fk,r)=q; V rows=d -> output cols fr=d)
#pragma unroll
    for (int ks = 0; ks < 2; ++ks){
      bf16x8 pa = *(const bf16x8*)&Ps[w*1024 + fr*64 + ((ks*4 + fk) ^ (fr & 7))*8];
#pragma unroll
      for (int n = 0; n < 4; ++n){
        int row = n*16 + fr;
        bf16x8 bv = *(const bf16x8*)&Vs[row*64 + ((ks*4 + fk) ^ (row & 7))*8];
        oacc[n] = __builtin_amdgcn_mfma_f32_16x16x32_bf16(pa, bv, oacc[n], 0,0,0);
      }
    }
  }

  // finalize: inv lives at q=fr lanes; transpose to (fk,r) rows
  float inv = 1.f / li;
  float invt[4];
#pragma unroll
  for (int r = 0; r < 4; ++r) invt[r] = __shfl(inv, fk*4 + r);

  int b = bh >> 4, h = bh & 15;
#pragma unroll
  for (int r = 0; r < 4; ++r){
    int q = q0 + w*16 + fk*4 + r;
#pragma unroll
    for (int n = 0; n < 4; ++n){
      int d = n*16 + fr;
      ctx[((size_t)(b*TT + q))*EMBED + h*HDIM + d] = f2bf(oacc[n][r]*invt[r]);
    }
  }
}

// ---------------- output projection (bf16 MFMA, fp32 + bias out) ----------------
__global__ __launch_bounds__(256)
void outproj_gemm(const u16* __restrict__ Ab, const u16* __restrict__ Bb,
                  const float* __restrict__ bias, float* __restrict__ C)
{
  __shared__ __align__(16) u16 Ah[128*32], Bh[128*32];
  const int t = threadIdx.x, lane = t & 63, w = t >> 6;
  const int wr = w >> 1, wc = w & 1;
  const int fr = lane & 15, fk = lane >> 4;
  const int m0 = blockIdx.y * 128, n0 = blockIdx.x * 128;

  f32x4 acc[4][4];
#pragma unroll
  for (int i = 0; i < 4; ++i)
#pragma unroll
    for (int j = 0; j < 4; ++j) acc[i][j] = (f32x4){0.f,0.f,0.f,0.f};

  for (int k0 = 0; k0 < EMBED; k0 += 32){
    __syncthreads();
#pragma unroll
    for (int cc = 0; cc < 2; ++cc){
      int cb = w*128 + cc*64;
      int chunk = cb + lane;
      int row = chunk >> 2, slot = chunk & 3;
      int sl = slot ^ swz4(row);
      stage16(Ab + (size_t)(m0+row)*EMBED + k0 + sl*8, Ah + cb*8);
      stage16(Bb + (size_t)(n0+row)*EMBED + k0 + sl*8, Bh + cb*8);
    }
    __syncthreads();

    bf16x8 ah[4], bh[4];
#pragma unroll
    for (int i = 0; i < 4; ++i){
      int ra = wr*64 + i*16 + fr;
      ah[i] = *(const bf16x8*)&Ah[ra*32 + (fk ^ swz4(ra))*8];
      int rb = wc*64 + i*16 + fr;
      bh[i] = *(const bf16x8*)&Bh[rb*32 + (fk ^ swz4(rb))*8];
    }
#pragma unroll
    for (int i = 0; i < 4; ++i)
#pragma unroll
      for (int j = 0; j < 4; ++j)
        acc[i][j] = __builtin_amdgcn_mfma_f32_16x16x32_bf16(ah[i], bh[j], acc[i][j], 0,0,0);
  }

#pragma unroll
  for (int i = 0; i < 4; ++i)
#pragma unroll
    for (int j = 0; j < 4; ++j)
#pragma unroll
      for (int r = 0; r < 4; ++r){
        int gm = m0 + wr*64 + i*16 + fk*4 + r;
        int gn = n0 + wc*64 + j*16 + fr;
        C[(size_t)gm*EMBED + gn] = acc[i][j][r] + bias[gn];
      }
}

// ---------------- launch ----------------
extern "C" void kernel_launch(void* const* d_in, const int* in_sizes, int n_in,
                              void* d_out, int out_size, void* d_ws, size_t ws_size,
                              hipStream_t stream) {
  const float* x  = (const float*)d_in[0];
  const float* Wq = (const float*)d_in[1];
  const float* Aq = (const float*)d_in[2];
  const float* Bq = (const float*)d_in[3];
  const float* Wk = (const float*)d_in[4];
  const float* Ak = (const float*)d_in[5];
  const float* Bk = (const float*)d_in[6];
  const float* Wv = (const float*)d_in[7];
  const float* Av = (const float*)d_in[8];
  const float* Bv = (const float*)d_in[9];
  const float* Wo = (const float*)d_in[10];
  const float* bo = (const float*)d_in[11];
  float* out = (float*)d_out;

  char* ws = (char*)d_ws;
  const size_t MB = 1u << 20;
  u16* xhi  = (u16*)(ws + 0*MB);    // 8 MB (aliased by ctx later)
  u16* xlo  = (u16*)(ws + 8*MB);    // 8 MB
  u16* whi  = (u16*)(ws + 16*MB);   // 6 MB  [Wq;Wk;Wv] hi
  u16* wlo  = (u16*)(ws + 22*MB);   // 6 MB
  u16* wob  = (u16*)(ws + 28*MB);   // 2 MB
  u16* qhi  = (u16*)(ws + 30*MB);   // 8 MB
  u16* qlo  = (u16*)(ws + 38*MB);   // 8 MB
  u16* khi  = (u16*)(ws + 46*MB);   // 8 MB
  u16* klo  = (u16*)(ws + 54*MB);   // 8 MB
  u16* vt   = (u16*)(ws + 62*MB);   // 8 MB
  u16* ctx  = (u16*)(ws + 0*MB);    // 8 MB, over xhi (dead after qkv_gemm)

  dim3 blk(256);
  split_x_kernel<<<dim3(MTOT*EMBED/256), blk, 0, stream>>>(x, xhi, xlo);
  prep_weights_kernel<<<dim3(4096, 4), blk, 0, stream>>>(Wq, Wk, Wv, Wo, Aq, Ak, Av,
                                                         Bq, Bk, Bv, whi, wlo, wob);

  qkv_gemm<<<dim3(3*EMBED/128, MTOT/128), blk, 0, stream>>>(xhi, xlo, whi, wlo,
                                                            qhi, qlo, khi, klo, vt);

  attn_mfma<<<dim3(TT/64, BH), blk, 0, stream>>>(qhi, qlo, khi, klo, vt, ctx);

  outproj_gemm<<<dim3(EMBED/128, MTOT/128), blk, 0, stream>>>(ctx, wob, bo, out);
}